// Round 16
// baseline (245.475 us; speedup 1.0000x reference)
//
#include <hip/hip_runtime.h>
#include <hip/hip_bf16.h>

#define NTOK 16384
#define HID 7168
#define NEXP 256
#define TOPK 8

typedef __bf16 bf16x8 __attribute__((ext_vector_type(8)));
typedef float  f32x16 __attribute__((ext_vector_type(16)));

// Weights, MFMA-fragment-linear (R12-proven layout):
// uint4 idx = ((p8*8 + g)*8 + ks)*64 + lane holds
// B[e = g*32 + (lane&31)][k = p8*128 + ks*16 + (lane>>5)*8 .. +8]
__device__ __align__(16) unsigned short g_wb[NEXP * HID];

__device__ __forceinline__ unsigned int f2bfb(float x) {
    unsigned int u = __float_as_uint(x);
    return (u + 0x7fffu + ((u >> 16) & 1u)) >> 16;
}
__device__ __forceinline__ uint4 pk4(float4 p, float4 q) {
    uint4 u;
    u.x = f2bfb(p.x) | (f2bfb(p.y) << 16);
    u.y = f2bfb(p.z) | (f2bfb(p.w) << 16);
    u.z = f2bfb(q.x) | (f2bfb(q.y) << 16);
    u.w = f2bfb(q.z) | (f2bfb(q.w) << 16);
    return u;
}
__device__ __forceinline__ bf16x8 asbf8(uint4 u) {
    union { uint4 a; bf16x8 b; } c; c.a = u; return c.b;
}

__global__ void wconv_frag(const float* __restrict__ wt) {
    const int tid = blockIdx.x * 256 + threadIdx.x;
    const int l  = tid & 63;
    const int ks = (tid >> 6) & 7;
    const int g  = (tid >> 9) & 7;
    const int p  = tid >> 12;
    const int e  = g * 32 + (l & 31);
    const int kb = p * 128 + ks * 16 + ((l >> 5) << 3);
    const float4* s = (const float4*)(wt + (size_t)e * HID + kb);
    ((uint4*)g_wb)[tid] = pk4(s[0], s[1]);
}

__global__ void moe_rows(float* __restrict__ ob) {
    const int q = blockIdx.x * 256 + threadIdx.x;
    ob[262144 + q] = (float)((q & 7) * NTOK + (q >> 3));
}

// Block 256 thr = 4 waves; wave w: 32 tokens x experts [w*64, +64).
// A: one 64-KB LDS mega-chunk (32 tok x 1024 k bf16, XOR-swizzled), restaged
// 7x with the only block-wide barriers. B: depth-4 register pipeline from g_wb.
__global__ __launch_bounds__(256, 2) void moe_gate_v16(
    const float* __restrict__ hs,
    float* __restrict__ ob)
{
    __shared__ __align__(16) char smem[65536];

    const int tid   = threadIdx.x;
    const int lane  = tid & 63;
    const int w     = tid >> 6;        // 0..3
    const int khalf = lane >> 5;
    const int t0    = blockIdx.x * 32;

    // ---- A staging map: thread = (row = tid>>3, sub = tid&7) ----
    const int srow = tid >> 3;
    const int ssub = tid & 7;
    const char* astage = (const char*)(hs + (size_t)(t0 + srow) * HID + ssub * 8);
    const int stBase = srow * 2048 + ((ssub * 16) ^ ((srow & 7) << 4));

    // ---- A fragment read geometry ----
    const int arow  = lane & 31;
    const int abase = arow * 2048;
    const int aswz  = (arow & 7) << 4;

    // ---- B fragment-linear per-lane base; wave w covers groups w*2, w*2+1 ----
    const char* const bbase = (const char*)g_wb + (size_t)(w * 2) * 8192 + lane * 16;

    f32x16 acc0 = {}, acc1 = {};
    uint4 b0a, b0b, b1a, b1b, b2a, b2b, b3a, b3b;   // 4 sets x 2 (static names)

#define ISSUE_B(SA, SB, J)                                                    \
    do {                                                                      \
        const char* bp = bbase + ((size_t)((J) >> 3) * 64 + ((J) & 7)) * 1024;\
        SA = *(const uint4*)(bp);                                             \
        SB = *(const uint4*)(bp + 8192);                                      \
        __builtin_amdgcn_sched_barrier(0);                                    \
    } while (0)

#define COMPUTE(JL, SA, SB)                                                   \
    do {                                                                      \
        const int off = (((JL) * 32 + khalf * 16) ^ aswz);                    \
        bf16x8 a = *(const bf16x8*)(smem + abase + off);                      \
        acc0 = __builtin_amdgcn_mfma_f32_32x32x16_bf16(a, asbf8(SA), acc0, 0, 0, 0); \
        acc1 = __builtin_amdgcn_mfma_f32_32x32x16_bf16(a, asbf8(SB), acc1, 0, 0, 0); \
    } while (0)

#define VMW(N)                                                                \
    do {                                                                      \
        asm volatile("s_waitcnt vmcnt(" #N ")" ::: "memory");                 \
        __builtin_amdgcn_sched_barrier(0);                                    \
    } while (0)

    for (int c = 0; c < 7; ++c) {
        // ---- stage A mega-chunk c (f32 -> bf16, swizzled) ----
        __syncthreads();                 // prior chunk's reads done; FIFO empty
        #pragma unroll
        for (int i = 0; i < 16; ++i) {
            float4 v0 = *(const float4*)(astage + (size_t)c * 4096 + i * 256);
            float4 v1 = *(const float4*)(astage + (size_t)c * 4096 + i * 256 + 16);
            *(uint4*)(smem + stBase + i * 128) = pk4(v0, v1);
        }
        __syncthreads();                 // chunk staged

        const int C64 = c * 64;
        // ---- B prologue: sets for local steps 0..3 ----
        ISSUE_B(b0a, b0b, C64 + 0);
        ISSUE_B(b1a, b1b, C64 + 1);
        ISSUE_B(b2a, b2b, C64 + 2);
        ISSUE_B(b3a, b3b, C64 + 3);

        // ---- 64 K-steps, depth-4 B pipeline, no barriers ----
        for (int jj = 0; jj < 15; ++jj) {
            const int j = jj * 4;
            VMW(6); COMPUTE(j + 0, b0a, b0b); ISSUE_B(b0a, b0b, C64 + j + 4);
            VMW(6); COMPUTE(j + 1, b1a, b1b); ISSUE_B(b1a, b1b, C64 + j + 5);
            VMW(6); COMPUTE(j + 2, b2a, b2b); ISSUE_B(b2a, b2b, C64 + j + 6);
            VMW(6); COMPUTE(j + 3, b3a, b3b); ISSUE_B(b3a, b3b, C64 + j + 7);
        }
        VMW(6); COMPUTE(60, b0a, b0b);
        VMW(4); COMPUTE(61, b1a, b1b);
        VMW(2); COMPUTE(62, b2a, b2b);
        VMW(0); COMPUTE(63, b3a, b3b);
    }

    __syncthreads();                     // alias smem for epilogue

    // ---- epilogue: logits [32][257] f32 ----
    float* ll = (float*)smem;
    {
        const int ec = w * 64 + (lane & 31);
        #pragma unroll
        for (int r = 0; r < 16; ++r) {
            const int tok = (r & 3) + 8 * (r >> 2) + 4 * khalf;
            ll[tok * 257 + ec]      = acc0[r];
            ll[tok * 257 + ec + 32] = acc1[r];
        }
    }
    __syncthreads();

    if (tid < 32) {
        const float* lr = ll + tid * 257;
        float bv[TOPK]; int bi8[TOPK];
        #pragma unroll
        for (int k = 0; k < TOPK; ++k) { bv[k] = -1e30f; bi8[k] = 0; }
        for (int e = 0; e < NEXP; ++e) {
            const float v = lr[e];
            if (v > bv[TOPK - 1]) {
                int k = TOPK - 1;
                while (k > 0 && v > bv[k - 1]) {
                    bv[k] = bv[k - 1]; bi8[k] = bi8[k - 1]; --k;
                }
                bv[k] = v; bi8[k] = e;      // strict > : ties keep lower idx
            }
        }
        float ev[TOPK], ssum = 0.f;
        #pragma unroll
        for (int r = 0; r < TOPK; ++r) { ev[r] = expf(bv[r] - bv[0]); ssum += ev[r]; }
        const float inv = 1.0f / ssum;

        const int tg = t0 + tid;
        #pragma unroll
        for (int r = 0; r < TOPK; ++r) {
            ob[(size_t)tg * TOPK + r]          = (float)bi8[r];   // idx
            ob[131072 + (size_t)tg * TOPK + r] = ev[r] * inv;     // weight
        }
    }
#undef ISSUE_B
#undef COMPUTE
#undef VMW
}

extern "C" void kernel_launch(void* const* d_in, const int* in_sizes, int n_in,
                              void* d_out, int out_size, void* d_ws, size_t ws_size,
                              hipStream_t stream) {
    const float* hs = (const float*)d_in[0];   // [16384, 7168] f32
    const float* wt = (const float*)d_in[1];   // [256, 7168] f32
    float* ob = (float*)d_out;                 // f32[393216]: idx | weight | row

    wconv_frag<<<dim3(NEXP * HID / 8 / 256), dim3(256), 0, stream>>>(wt);
    moe_gate_v16<<<dim3(NTOK / 32), dim3(256), 0, stream>>>(hs, ob);
    moe_rows<<<dim3(512), dim3(256), 0, stream>>>(ob);
}